// Round 8
// baseline (138.129 us; speedup 1.0000x reference)
//
#include <hip/hip_runtime.h>
#include <math.h>

// Problem constants: B=4, H=W=1024, GH=GW=16, GD=8, C=12
// ws layout: gridbuf[((b*16+gh)*16+gw)*96 + z*12 + c], then params[81]
// params: [w_r x16][w_g x16][w_b x16][bias x16][g2w x16][g2b]

#define GRIDBUF_FLOATS (4 * 16 * 16 * 96)
// fp16 LDS layout: dword offset = wc*CELL_U32 + z*8 + qpair (qpair 0..5, ch pair)
#define CELL_U32 68   // 68 mod 32 = 4 -> neighbor cells shift banks; z*8 tiles the rest

typedef float    f2  __attribute__((ext_vector_type(2)));
typedef int      i2  __attribute__((ext_vector_type(2)));
typedef _Float16 h2  __attribute__((ext_vector_type(2)));

__device__ inline f2 splat2(float x) { f2 v; v.x = x; v.y = x; return v; }
__device__ inline h2 hsplat(float x) { _Float16 h = (_Float16)x; h2 v; v.x = h; v.y = h; return v; }
__device__ inline h2 u2h(unsigned int u) { return __builtin_bit_cast(h2, u); }

// packed tanh on a pair: t = sign(x) * (1 - 2/(exp(2|x|)+1))
__device__ inline f2 fast_tanh2(f2 x) {
    f2 ax = __builtin_elementwise_abs(x);
    f2 xx = ax + ax;
    f2 e;
    e.x = __expf(xx.x);
    e.y = __expf(xx.y);
    f2 ep1 = e + splat2(1.0f);
    f2 r;
    r.x = __builtin_amdgcn_rcpf(ep1.x);
    r.y = __builtin_amdgcn_rcpf(ep1.y);
    f2 t = splat2(1.0f) - (r + r);          // in [0,1], e=inf -> t=1
    i2 sgn = __builtin_bit_cast(i2, x) & (i2){(int)0x80000000, (int)0x80000000};
    return __builtin_bit_cast(f2, __builtin_bit_cast(i2, t) | sgn);
}

// ---------------- Kernel 1: grid coefficients + folded guide params ----------
__global__ __launch_bounds__(128) void coeff_kernel(
    const float* __restrict__ lf,    // (B,64,16,16)
    const float* __restrict__ gf,    // (B,64)
    const float* __restrict__ fw,    // (96,64)
    const float* __restrict__ fb,    // (96,)
    const float* __restrict__ g1w,   // (16,3)
    const float* __restrict__ g1b,   // (16,)
    const float* __restrict__ bng,
    const float* __restrict__ bnb,
    const float* __restrict__ bnm,
    const float* __restrict__ bnv,
    const float* __restrict__ g2w,   // (1,16)
    const float* __restrict__ g2b,   // (1,)
    float* __restrict__ gridbuf,     // (B,16,16,96)
    float* __restrict__ params)      // 81 floats
{
    __shared__ float fused[64];
    const int blk = blockIdx.x;       // b*256 + pos
    const int b   = blk >> 8;
    const int pos = blk & 255;
    const int t   = threadIdx.x;

    if (t < 64) {
        float v = lf[(b * 64 + t) * 256 + pos] + gf[b * 64 + t];
        fused[t] = v > 0.0f ? v : 0.0f;
    }
    __syncthreads();

    if (t < 96) {
        float acc = fb[t];
        const float* wrow = fw + t * 64;
#pragma unroll
        for (int i = 0; i < 64; ++i) acc = fmaf(wrow[i], fused[i], acc);
        gridbuf[blk * 96 + t] = acc;
    }

    if (blk == 0 && t >= 96 && t < 112) {
        int k = t - 96;
        float a = bng[k] * rsqrtf(bnv[k] + 1e-5f);
        params[k]      = g1w[k * 3 + 0] * a;
        params[16 + k] = g1w[k * 3 + 1] * a;
        params[32 + k] = g1w[k * 3 + 2] * a;
        params[48 + k] = (g1b[k] - bnm[k]) * a + bnb[k];
        params[64 + k] = g2w[k];
        if (k == 0) params[80] = g2b[0];
    }
}

// ---------------- Kernel 2: guide + bilateral slice + apply + tanh -----------
// 8192 blocks x 256 threads, one block = half an image row, 2 px/thread (R7).
// NEW: hrow stored as packed fp16 channel-pairs -> per-corner LDS read is
// b128+b64 (6 dwords) instead of 3x b128 (12 dwords); lerp in v_pk_fma_f16.
__global__ __launch_bounds__(256) void slice_apply_kernel(
    const float* __restrict__ fullres,  // (B,3,1024,1024)
    const float* __restrict__ gridbuf,  // (B,16,16,96)
    const float* __restrict__ params,   // 81 floats (uniform -> s_load)
    float* __restrict__ out)            // (B,3,1024,1024)
{
    __shared__ __align__(16) unsigned int hrowu[16 * CELL_U32];   // 4.25 KB

    const int t    = threadIdx.x;
    const int blk  = blockIdx.x;
    const int b    = blk >> 11;
    const int rem  = blk & 2047;
    const int y    = rem >> 1;
    const int half = rem & 1;
    const int x0   = half << 9;

    const int xb      = x0 + (t << 1);           // 2 pixels per thread
    const int pixbase = (y << 10) + xb;
    const int planeB  = (b * 3) << 20;

    // issue pixel loads early (in flight during fill + barrier); nontemporal:
    // fullres has zero reuse, keep L2 for gridbuf
    f2 rr = __builtin_nontemporal_load((const f2*)(fullres + planeB + (0 << 20) + pixbase));
    f2 gg = __builtin_nontemporal_load((const f2*)(fullres + planeB + (1 << 20) + pixbase));
    f2 bb = __builtin_nontemporal_load((const f2*)(fullres + planeB + (2 << 20) + pixbase));

    // ---- fill: 9 cells cover this half-row; h-lerp fp32 -> RNE fp16 pairs ----
    const int cbase = half * 7;                  // half0: cells 0..8, half1: 7..15
    {
        const int h0i  = (y < 32) ? -1 : ((y - 32) >> 6);
        const float fh = ((float)y * 0.015625f + (0.0078125f - 0.5f)) - (float)h0i;
        const int hc0  = h0i < 0 ? 0 : h0i;
        const int hc1  = (h0i + 1) > 15 ? 15 : (h0i + 1);
        const float* row0 = gridbuf + (b * 256 + hc0 * 16) * 96;
        const float* row1 = gridbuf + (b * 256 + hc1 * 16) * 96;
        const float wfh0 = 1.0f - fh;
        if (t < 216) {                           // 9 cells * 8 z * 3 quads
            const int cell = cbase + t / 24;
            const int rz   = t % 24;
            const int z    = rz / 3;
            const int q2   = rz % 3;             // float quad within the z-row
            const int gi   = cell * 96 + z * 12 + q2 * 4;
            float4 a = *(const float4*)(row0 + gi);
            float4 c = *(const float4*)(row1 + gi);
            float4 r;
            r.x = fmaf(wfh0, a.x, fh * c.x);
            r.y = fmaf(wfh0, a.y, fh * c.y);
            r.z = fmaf(wfh0, a.z, fh * c.z);
            r.w = fmaf(wfh0, a.w, fh * c.w);
            h2 p0; p0.x = (_Float16)r.x; p0.y = (_Float16)r.y;
            h2 p1; p1.x = (_Float16)r.z; p1.y = (_Float16)r.w;
            uint2 wv;
            wv.x = __builtin_bit_cast(unsigned int, p0);
            wv.y = __builtin_bit_cast(unsigned int, p1);
            *(uint2*)(hrowu + cell * CELL_U32 + z * 8 + 2 * q2) = wv;
        }
    }
    __syncthreads();

    // w cells: shared by both pixels (boundaries at x=32+64k are even; xb even)
    const int w0i = (xb < 32) ? -1 : ((xb - 32) >> 6);
    const int wc0 = w0i < 0 ? 0 : w0i;
    const int wc1 = (w0i + 1) > 15 ? 15 : (w0i + 1);
    const float fw0 = (float)xb * 0.015625f + (0.0078125f - 0.5f) - (float)w0i;
    const unsigned int* cell0 = hrowu + wc0 * CELL_U32;
    const unsigned int* cell1 = hrowu + wc1 * CELL_U32;

    // ---- guide MLP, packed across the pixel pair (fp32) ----
    f2 acc = splat2(params[80]);
#pragma unroll
    for (int k = 0; k < 16; ++k) {
        f2 gk = __builtin_elementwise_fma(rr, splat2(params[k]),
                __builtin_elementwise_fma(gg, splat2(params[16 + k]),
                __builtin_elementwise_fma(bb, splat2(params[32 + k]),
                                          splat2(params[48 + k]))));
        gk = __builtin_elementwise_max(gk, splat2(0.0f));
        acc = __builtin_elementwise_fma(gk, splat2(params[64 + k]), acc);
    }
    f2 zg;
    zg.x = fmaf(8.0f, __builtin_amdgcn_rcpf(1.0f + __expf(-acc.x)), -0.5f);
    zg.y = fmaf(8.0f, __builtin_amdgcn_rcpf(1.0f + __expf(-acc.y)), -0.5f);

    f2 Rp, Gp, Bp;
#pragma unroll
    for (int px = 0; px < 2; ++px) {
        const float zgp = px ? zg.y : zg.x;
        int   z0 = (int)floorf(zgp);
        float fz = zgp - (float)z0;
        int zc0 = z0 < 0 ? 0 : z0;
        int zc1 = (z0 + 1) > 7 ? 7 : (z0 + 1);

        const float fw_ = fw0 + (float)px * 0.015625f;
        const float ww0 = 1.0f - fw_;
        const h2 W00 = hsplat(ww0 * (1.0f - fz));
        const h2 W01 = hsplat(ww0 * fz);
        const h2 W10 = hsplat(fw_ * (1.0f - fz));
        const h2 W11 = hsplat(fw_ * fz);

        // 4 corners, 6 dwords each: b128 + b64
        const unsigned int* a00 = cell0 + zc0 * 8;
        const unsigned int* a01 = cell0 + zc1 * 8;
        const unsigned int* a10 = cell1 + zc0 * 8;
        const unsigned int* a11 = cell1 + zc1 * 8;
        uint4 A0 = *(const uint4*)a00; uint2 A0t = *(const uint2*)(a00 + 4);
        uint4 A1 = *(const uint4*)a01; uint2 A1t = *(const uint2*)(a01 + 4);
        uint4 B0 = *(const uint4*)a10; uint2 B0t = *(const uint2*)(a10 + 4);
        uint4 B1 = *(const uint4*)a11; uint2 B1t = *(const uint2*)(a11 + 4);

        // s[q] = c00*W00 + c01*W01 + c10*W10 + c11*W11  (packed f16, 4 fma/q)
        h2 s[6];
        {
            unsigned int c00[6] = {A0.x, A0.y, A0.z, A0.w, A0t.x, A0t.y};
            unsigned int c01[6] = {A1.x, A1.y, A1.z, A1.w, A1t.x, A1t.y};
            unsigned int c10[6] = {B0.x, B0.y, B0.z, B0.w, B0t.x, B0t.y};
            unsigned int c11[6] = {B1.x, B1.y, B1.z, B1.w, B1t.x, B1t.y};
#pragma unroll
            for (int q = 0; q < 6; ++q) {
                s[q] = __builtin_elementwise_fma(u2h(c00[q]), W00,
                       __builtin_elementwise_fma(u2h(c01[q]), W01,
                       __builtin_elementwise_fma(u2h(c10[q]), W10,
                                                 u2h(c11[q]) * W11)));
            }
        }

        // unpack to fp32: ch pair q -> (2q, 2q+1)
        const float s0  = (float)s[0].x, s1  = (float)s[0].y;
        const float s2  = (float)s[1].x, s3  = (float)s[1].y;
        const float s4  = (float)s[2].x, s5  = (float)s[2].y;
        const float s6  = (float)s[3].x, s7  = (float)s[3].y;
        const float s8  = (float)s[4].x, s9  = (float)s[4].y;
        const float s10 = (float)s[5].x, s11 = (float)s[5].y;

        const float rs = px ? rr.y : rr.x;
        const float gs = px ? gg.y : gg.x;
        const float bs = px ? bb.y : bb.x;
        float Rv = fmaf(rs, s0, fmaf(gs, s1, fmaf(bs, s2, s9)));
        float Gv = fmaf(rs, s3, fmaf(gs, s4, fmaf(bs, s5, s10)));
        float Bv = fmaf(rs, s6, fmaf(gs, s7, fmaf(bs, s8, s11)));
        if (px == 0) { Rp.x = Rv; Gp.x = Gv; Bp.x = Bv; }
        else         { Rp.y = Rv; Gp.y = Gv; Bp.y = Bv; }
    }

    f2 tR = fast_tanh2(Rp);
    f2 tG = fast_tanh2(Gp);
    f2 tB = fast_tanh2(Bp);

    __builtin_nontemporal_store(tR, (f2*)(out + planeB + (0 << 20) + pixbase));
    __builtin_nontemporal_store(tG, (f2*)(out + planeB + (1 << 20) + pixbase));
    __builtin_nontemporal_store(tB, (f2*)(out + planeB + (2 << 20) + pixbase));
}

extern "C" void kernel_launch(void* const* d_in, const int* in_sizes, int n_in,
                              void* d_out, int out_size, void* d_ws, size_t ws_size,
                              hipStream_t stream) {
    const float* fullres = (const float*)d_in[0];
    const float* lf      = (const float*)d_in[1];
    const float* gf      = (const float*)d_in[2];
    const float* fw      = (const float*)d_in[3];
    const float* fb      = (const float*)d_in[4];
    const float* g1w     = (const float*)d_in[5];
    const float* g1b     = (const float*)d_in[6];
    const float* bng     = (const float*)d_in[7];
    const float* bnb     = (const float*)d_in[8];
    const float* bnm     = (const float*)d_in[9];
    const float* bnv     = (const float*)d_in[10];
    const float* g2w     = (const float*)d_in[11];
    const float* g2b     = (const float*)d_in[12];
    float* out = (float*)d_out;

    float* gridbuf = (float*)d_ws;
    float* params  = gridbuf + GRIDBUF_FLOATS;

    coeff_kernel<<<4 * 256, 128, 0, stream>>>(lf, gf, fw, fb, g1w, g1b,
                                              bng, bnb, bnm, bnv, g2w, g2b,
                                              gridbuf, params);
    slice_apply_kernel<<<4 * 2048, 256, 0, stream>>>(fullres, gridbuf, params, out);
}

// Round 9
// 132.340 us; speedup vs baseline: 1.0437x; 1.0437x over previous
//
#include <hip/hip_runtime.h>
#include <math.h>

// Problem constants: B=4, H=W=1024, GH=GW=16, GD=8, C=12
// ws layout: gridbuf[((b*16+gh)*16+gw)*96 + z*12 + c], then params[81]
// params: [w_r x16][w_g x16][w_b x16][bias x16][g2w x16][g2b]

#define GRIDBUF_FLOATS (4 * 16 * 16 * 96)
#define CELL_STRIDE 100   // padded from 96: banks shift by 4 per wc

typedef float  f2  __attribute__((ext_vector_type(2)));
typedef int    i2  __attribute__((ext_vector_type(2)));

__device__ inline f2 splat2(float x) { f2 v; v.x = x; v.y = x; return v; }

// packed tanh on a pair: t = sign(x) * (1 - 2/(exp(2|x|)+1))
__device__ inline f2 fast_tanh2(f2 x) {
    f2 ax = __builtin_elementwise_abs(x);
    f2 xx = ax + ax;
    f2 e;
    e.x = __expf(xx.x);
    e.y = __expf(xx.y);
    f2 ep1 = e + splat2(1.0f);
    f2 r;
    r.x = __builtin_amdgcn_rcpf(ep1.x);
    r.y = __builtin_amdgcn_rcpf(ep1.y);
    f2 t = splat2(1.0f) - (r + r);          // in [0,1], e=inf -> t=1
    i2 sgn = __builtin_bit_cast(i2, x) & (i2){(int)0x80000000, (int)0x80000000};
    return __builtin_bit_cast(f2, __builtin_bit_cast(i2, t) | sgn);
}

// ---------------- Kernel 1: grid coefficients + folded guide params ----------
__global__ __launch_bounds__(128) void coeff_kernel(
    const float* __restrict__ lf,    // (B,64,16,16)
    const float* __restrict__ gf,    // (B,64)
    const float* __restrict__ fw,    // (96,64)
    const float* __restrict__ fb,    // (96,)
    const float* __restrict__ g1w,   // (16,3)
    const float* __restrict__ g1b,   // (16,)
    const float* __restrict__ bng,
    const float* __restrict__ bnb,
    const float* __restrict__ bnm,
    const float* __restrict__ bnv,
    const float* __restrict__ g2w,   // (1,16)
    const float* __restrict__ g2b,   // (1,)
    float* __restrict__ gridbuf,     // (B,16,16,96)
    float* __restrict__ params)      // 81 floats
{
    __shared__ float fused[64];
    const int blk = blockIdx.x;       // b*256 + pos
    const int b   = blk >> 8;
    const int pos = blk & 255;
    const int t   = threadIdx.x;

    if (t < 64) {
        float v = lf[(b * 64 + t) * 256 + pos] + gf[b * 64 + t];
        fused[t] = v > 0.0f ? v : 0.0f;
    }
    __syncthreads();

    if (t < 96) {
        float acc = fb[t];
        const float* wrow = fw + t * 64;
#pragma unroll
        for (int i = 0; i < 64; ++i) acc = fmaf(wrow[i], fused[i], acc);
        gridbuf[blk * 96 + t] = acc;
    }

    if (blk == 0 && t >= 96 && t < 112) {
        int k = t - 96;
        float a = bng[k] * rsqrtf(bnv[k] + 1e-5f);
        params[k]      = g1w[k * 3 + 0] * a;
        params[16 + k] = g1w[k * 3 + 1] * a;
        params[32 + k] = g1w[k * 3 + 2] * a;
        params[48 + k] = (g1b[k] - bnm[k]) * a + bnb[k];
        params[64 + k] = g2w[k];
        if (k == 0) params[80] = g2b[0];
    }
}

// ---------------- Kernel 2: guide + bilateral slice + apply + tanh -----------
// 2048 blocks x 256 threads. Block i = half-row (y=i>>1, half=i&1), iterated
// over the 4 images (b = it). All h/w indexing is loop-invariant; hrow is
// double-buffered; next image's gridbuf rows + fullres pixels prefetch during
// compute of the current image (hides L2/HBM latency behind ~1.5k cyc VALU).
__global__ __launch_bounds__(256) void slice_apply_kernel(
    const float* __restrict__ fullres,  // (B,3,1024,1024)
    const float* __restrict__ gridbuf,  // (B,16,16,96)
    const float* __restrict__ params,   // 81 floats (uniform -> s_load)
    float* __restrict__ out)            // (B,3,1024,1024)
{
    __shared__ __align__(16) float hbuf[2][16 * CELL_STRIDE];   // 2 x 6.4 KB

    const int t    = threadIdx.x;
    const int i    = blockIdx.x;        // 0..2047 half-row id
    const int y    = i >> 1;
    const int half = i & 1;
    const int xb   = (half << 9) + (t << 1);     // 2 pixels per thread
    const int pixbase = (y << 10) + xb;

    // ---- loop-invariant h interpolation params ----
    const int h0i  = (y < 32) ? -1 : ((y - 32) >> 6);
    const float fh = ((float)y * 0.015625f + (0.0078125f - 0.5f)) - (float)h0i;
    const int hc0  = h0i < 0 ? 0 : h0i;
    const int hc1  = (h0i + 1) > 15 ? 15 : (h0i + 1);
    const float wfh0 = 1.0f - fh;

    // ---- loop-invariant fill addressing (9 cells cover this half-row) ----
    const int cbase = half * 7;                  // half0: cells 0..8, half1: 7..15
    const int fi   = cbase * 96 + (t << 2);      // float index in grid row
    const int fwc  = fi / 96;
    const int frm  = fi - fwc * 96;
    const int fill_off = fwc * CELL_STRIDE + frm;
    const float* grow0 = gridbuf + hc0 * 16 * 96 + fi;   // image 0
    const float* grow1 = gridbuf + hc1 * 16 * 96 + fi;

    // ---- loop-invariant w cell params (both px share: xb even, bounds even) ----
    const int w0i = (xb < 32) ? -1 : ((xb - 32) >> 6);
    const int wc0 = w0i < 0 ? 0 : w0i;
    const int wc1 = (w0i + 1) > 15 ? 15 : (w0i + 1);
    const float fw0 = (float)xb * 0.015625f + (0.0078125f - 0.5f) - (float)w0i;

    // ---- prologue: issue image-0 loads ----
    float4 ga, gc;
    if (t < 216) {
        ga = *(const float4*)grow0;
        gc = *(const float4*)grow1;
    }
    f2 rr = *(const f2*)(fullres + pixbase);
    f2 gg = *(const f2*)(fullres + (1 << 20) + pixbase);
    f2 bb = *(const f2*)(fullres + (2 << 20) + pixbase);

#pragma unroll
    for (int it = 0; it < 4; ++it) {
        float* buf = hbuf[it & 1];

        // fill this image's h-lerped row into the current buffer
        if (t < 216) {
            float4 r;
            r.x = fmaf(wfh0, ga.x, fh * gc.x);
            r.y = fmaf(wfh0, ga.y, fh * gc.y);
            r.z = fmaf(wfh0, ga.z, fh * gc.z);
            r.w = fmaf(wfh0, ga.w, fh * gc.w);
            *(float4*)(buf + fill_off) = r;
        }

        // prefetch next image (consumed next iteration, hidden behind compute)
        f2 nrr, ngg, nbb;
        float4 nga, ngc;
        if (it < 3) {
            const float* fr = fullres + (((it + 1) * 3) << 20) + pixbase;
            nrr = *(const f2*)fr;
            ngg = *(const f2*)(fr + (1 << 20));
            nbb = *(const f2*)(fr + (2 << 20));
            if (t < 216) {
                nga = *(const float4*)(grow0 + (it + 1) * 24576);
                ngc = *(const float4*)(grow1 + (it + 1) * 24576);
            }
        }
        __syncthreads();

        const float* cell0 = buf + wc0 * CELL_STRIDE;
        const float* cell1 = buf + wc1 * CELL_STRIDE;

        // ---- guide MLP, packed across the pixel pair ----
        f2 acc = splat2(params[80]);
#pragma unroll
        for (int k = 0; k < 16; ++k) {
            f2 gk = __builtin_elementwise_fma(rr, splat2(params[k]),
                    __builtin_elementwise_fma(gg, splat2(params[16 + k]),
                    __builtin_elementwise_fma(bb, splat2(params[32 + k]),
                                              splat2(params[48 + k]))));
            gk = __builtin_elementwise_max(gk, splat2(0.0f));
            acc = __builtin_elementwise_fma(gk, splat2(params[64 + k]), acc);
        }
        f2 zg;
        zg.x = fmaf(8.0f, __builtin_amdgcn_rcpf(1.0f + __expf(-acc.x)), -0.5f);
        zg.y = fmaf(8.0f, __builtin_amdgcn_rcpf(1.0f + __expf(-acc.y)), -0.5f);

        f2 Rp, Gp, Bp;
#pragma unroll
        for (int px = 0; px < 2; ++px) {
            const float zgp = px ? zg.y : zg.x;
            int   z0 = (int)floorf(zgp);
            float fz = zgp - (float)z0;
            int zc0 = z0 < 0 ? 0 : z0;
            int zc1 = (z0 + 1) > 7 ? 7 : (z0 + 1);

            const float fw_ = fw0 + (float)px * 0.015625f;
            const float ww0 = 1.0f - fw_;
            const f2 W00 = splat2(ww0 * (1.0f - fz));
            const f2 W01 = splat2(ww0 * fz);
            const f2 W10 = splat2(fw_ * (1.0f - fz));
            const f2 W11 = splat2(fw_ * fz);

            const float4* p00 = (const float4*)(cell0 + zc0 * 12);
            const float4* p01 = (const float4*)(cell0 + zc1 * 12);
            const float4* p10 = (const float4*)(cell1 + zc0 * 12);
            const float4* p11 = (const float4*)(cell1 + zc1 * 12);

            f2 sa[6];   // channel-packed: {s0,s1}..{s10,s11}
#pragma unroll
            for (int q = 0; q < 3; ++q) {
                float4 a = p00[q], c = p01[q], d = p10[q], e = p11[q];
                f2 alo = (f2){a.x, a.y}, ahi = (f2){a.z, a.w};
                f2 clo = (f2){c.x, c.y}, chi = (f2){c.z, c.w};
                f2 dlo = (f2){d.x, d.y}, dhi = (f2){d.z, d.w};
                f2 elo = (f2){e.x, e.y}, ehi = (f2){e.z, e.w};
                sa[2 * q] =
                    __builtin_elementwise_fma(alo, W00,
                    __builtin_elementwise_fma(clo, W01,
                    __builtin_elementwise_fma(dlo, W10, elo * W11)));
                sa[2 * q + 1] =
                    __builtin_elementwise_fma(ahi, W00,
                    __builtin_elementwise_fma(chi, W01,
                    __builtin_elementwise_fma(dhi, W10, ehi * W11)));
            }

            const float rs = px ? rr.y : rr.x;
            const float gs = px ? gg.y : gg.x;
            const float bs = px ? bb.y : bb.x;
            float Rv = fmaf(rs, sa[0].x, fmaf(gs, sa[0].y, fmaf(bs, sa[1].x, sa[4].y)));
            float Gv = fmaf(rs, sa[1].y, fmaf(gs, sa[2].x, fmaf(bs, sa[2].y, sa[5].x)));
            float Bv = fmaf(rs, sa[3].x, fmaf(gs, sa[3].y, fmaf(bs, sa[4].x, sa[5].y)));
            if (px == 0) { Rp.x = Rv; Gp.x = Gv; Bp.x = Bv; }
            else         { Rp.y = Rv; Gp.y = Gv; Bp.y = Bv; }
        }

        f2 tR = fast_tanh2(Rp);
        f2 tG = fast_tanh2(Gp);
        f2 tB = fast_tanh2(Bp);

        float* ob = out + ((it * 3) << 20) + pixbase;
        __builtin_nontemporal_store(tR, (f2*)(ob));
        __builtin_nontemporal_store(tG, (f2*)(ob + (1 << 20)));
        __builtin_nontemporal_store(tB, (f2*)(ob + (2 << 20)));

        // rotate prefetched values in
        ga = nga; gc = ngc; rr = nrr; gg = ngg; bb = nbb;
    }
}

extern "C" void kernel_launch(void* const* d_in, const int* in_sizes, int n_in,
                              void* d_out, int out_size, void* d_ws, size_t ws_size,
                              hipStream_t stream) {
    const float* fullres = (const float*)d_in[0];
    const float* lf      = (const float*)d_in[1];
    const float* gf      = (const float*)d_in[2];
    const float* fw      = (const float*)d_in[3];
    const float* fb      = (const float*)d_in[4];
    const float* g1w     = (const float*)d_in[5];
    const float* g1b     = (const float*)d_in[6];
    const float* bng     = (const float*)d_in[7];
    const float* bnb     = (const float*)d_in[8];
    const float* bnm     = (const float*)d_in[9];
    const float* bnv     = (const float*)d_in[10];
    const float* g2w     = (const float*)d_in[11];
    const float* g2b     = (const float*)d_in[12];
    float* out = (float*)d_out;

    float* gridbuf = (float*)d_ws;
    float* params  = gridbuf + GRIDBUF_FLOATS;

    coeff_kernel<<<4 * 256, 128, 0, stream>>>(lf, gf, fw, fb, g1w, g1b,
                                              bng, bnb, bnm, bnv, g2w, g2b,
                                              gridbuf, params);
    slice_apply_kernel<<<2048, 256, 0, stream>>>(fullres, gridbuf, params, out);
}